// Round 2
// baseline (49.693 us; speedup 1.0000x reference)
//
#include <hip/hip_runtime.h>
#include <hip/hip_cooperative_groups.h>
#include <math.h>

namespace cg = cooperative_groups;

#define HDIM 512
#define LDIM 256
#define NGB 16          // gather blocks
#define ROWS_PER_GB 16  // L / NGB

// One cooperative kernel, 128 blocks x 256 threads, two grid syncs.
// ws layout: sp[NGB][4*HDIM] partial weighted sums, then t[2*HDIM].
__global__ void __launch_bounds__(256)
strnn_fused(const float* __restrict__ td_u, const float* __restrict__ td_l,
            const float* __restrict__ ld_u, const float* __restrict__ ld_l,
            const float* __restrict__ hx,   const float* __restrict__ W_ih,
            const float* __restrict__ W_thU, const float* __restrict__ W_thL,
            const float* __restrict__ W_shU, const float* __restrict__ W_shL,
            const float* __restrict__ table, const int* __restrict__ loc,
            float* __restrict__ sp, float* __restrict__ t, float* __restrict__ out) {
    cg::grid_group grid = cg::this_grid();
    __shared__ float smem[4 * HDIM];  // phase1: 64 floats of weights; phase2: full s (2048 floats)
    const int b    = blockIdx.x;
    const int tid  = threadIdx.x;
    const int wave = tid >> 6;
    const int lane = tid & 63;

    // ---- Phase 1: gather + 4 weighted row-sums, 16 partial blocks (no atomics) ----
    if (b < NGB) {
        if (tid < ROWS_PER_GB) {
            const int l = b * ROWS_PER_GB + tid;
            const float a1 = td_u[l], b1 = td_l[l];
            const float beta = a1 / (a1 + b1);
            const float a2 = ld_u[l], b2 = ld_l[l];
            const float alpha = a2 / (a2 + b2);
            smem[tid * 4 + 0] = alpha * beta;
            smem[tid * 4 + 1] = alpha * (1.0f - beta);
            smem[tid * 4 + 2] = (1.0f - alpha) * beta;
            smem[tid * 4 + 3] = (1.0f - alpha) * (1.0f - beta);
        }
        __syncthreads();
        const int h2 = tid * 2;  // 2 consecutive h per thread
        float a0x = 0, a0y = 0, a1x = 0, a1y = 0, a2x = 0, a2y = 0, a3x = 0, a3y = 0;
#pragma unroll 4
        for (int li = 0; li < ROWS_PER_GB; ++li) {
            const int l = b * ROWS_PER_GB + li;
            const size_t row = (size_t)loc[l] * HDIM;
            const float2 e = *(const float2*)(table + row + h2);
            const float w0 = smem[li * 4 + 0], w1 = smem[li * 4 + 1];
            const float w2 = smem[li * 4 + 2], w3 = smem[li * 4 + 3];
            a0x += w0 * e.x; a0y += w0 * e.y;
            a1x += w1 * e.x; a1y += w1 * e.y;
            a2x += w2 * e.x; a2y += w2 * e.y;
            a3x += w3 * e.x; a3y += w3 * e.y;
        }
        float* spb = sp + (size_t)b * (4 * HDIM);
        spb[0 * HDIM + h2] = a0x; spb[0 * HDIM + h2 + 1] = a0y;
        spb[1 * HDIM + h2] = a1x; spb[1 * HDIM + h2 + 1] = a1y;
        spb[2 * HDIM + h2] = a2x; spb[2 * HDIM + h2 + 1] = a2y;
        spb[3 * HDIM + h2] = a3x; spb[3 * HDIM + h2 + 1] = a3y;
    }
    grid.sync();

    // ---- Phase 2: reduce 16 partials into LDS, then t rows (one per wave) ----
    {
        const int e0 = tid * 8;  // 8 consecutive floats per thread
        float4 r0 = {0, 0, 0, 0}, r1 = {0, 0, 0, 0};
#pragma unroll 4
        for (int p = 0; p < NGB; ++p) {
            const float* spp = sp + (size_t)p * (4 * HDIM) + e0;
            const float4 u0 = *(const float4*)(spp);
            const float4 u1 = *(const float4*)(spp + 4);
            r0.x += u0.x; r0.y += u0.y; r0.z += u0.z; r0.w += u0.w;
            r1.x += u1.x; r1.y += u1.y; r1.z += u1.z; r1.w += u1.w;
        }
        *(float4*)(smem + e0)     = r0;
        *(float4*)(smem + e0 + 4) = r1;
    }
    __syncthreads();
    {
        const int i = b * 4 + wave;
        const float* wu = W_thU + (size_t)i * HDIM;
        const float* wl = W_thL + (size_t)i * HDIM;
        float pu = 0.f, pl = 0.f;
#pragma unroll
        for (int it = 0; it < 2; ++it) {
            const int j = it * 256 + lane * 4;
            const float4 u  = *(const float4*)(wu + j);
            const float4 l4 = *(const float4*)(wl + j);
            const float4 s1 = *(const float4*)(smem + 0 * HDIM + j);
            const float4 s2 = *(const float4*)(smem + 1 * HDIM + j);
            const float4 s3 = *(const float4*)(smem + 2 * HDIM + j);
            const float4 s4 = *(const float4*)(smem + 3 * HDIM + j);
            pu += u.x * s1.x + u.y * s1.y + u.z * s1.z + u.w * s1.w
                + l4.x * s2.x + l4.y * s2.y + l4.z * s2.z + l4.w * s2.w;
            pl += u.x * s3.x + u.y * s3.y + u.z * s3.z + u.w * s3.w
                + l4.x * s4.x + l4.y * s4.y + l4.z * s4.z + l4.w * s4.w;
        }
#pragma unroll
        for (int off = 32; off; off >>= 1) {
            pu += __shfl_down(pu, off);
            pl += __shfl_down(pl, off);
        }
        if (lane == 0) { t[i] = pu; t[HDIM + i] = pl; }
    }
    grid.sync();

    // ---- Phase 3: output rows (one per wave) ----
    {
        const int i = b * 4 + wave;
        const float* wu = W_shU + (size_t)i * HDIM;
        const float* wl = W_shL + (size_t)i * HDIM;
        const float* wi = W_ih + (size_t)i * HDIM;
        float p = 0.f;
#pragma unroll
        for (int it = 0; it < 2; ++it) {
            const int j = it * 256 + lane * 4;
            const float4 u   = *(const float4*)(wu + j);
            const float4 l4  = *(const float4*)(wl + j);
            const float4 wi4 = *(const float4*)(wi + j);
            const float4 tu  = *(const float4*)(t + j);
            const float4 tl  = *(const float4*)(t + HDIM + j);
            const float4 hv  = *(const float4*)(hx + j);
            p += u.x * tu.x + u.y * tu.y + u.z * tu.z + u.w * tu.w
               + l4.x * tl.x + l4.y * tl.y + l4.z * tl.z + l4.w * tl.w
               + wi4.x * hv.x + wi4.y * hv.y + wi4.z * hv.z + wi4.w * hv.w;
        }
#pragma unroll
        for (int off = 32; off; off >>= 1) p += __shfl_down(p, off);
        if (lane == 0) out[i] = 1.0f / (1.0f + expf(-p));
    }
}

extern "C" void kernel_launch(void* const* d_in, const int* in_sizes, int n_in,
                              void* d_out, int out_size, void* d_ws, size_t ws_size,
                              hipStream_t stream) {
    const float* td_u  = (const float*)d_in[0];
    const float* td_l  = (const float*)d_in[1];
    const float* ld_u  = (const float*)d_in[2];
    const float* ld_l  = (const float*)d_in[3];
    const float* hx    = (const float*)d_in[4];
    const float* W_ih  = (const float*)d_in[5];
    const float* W_thU = (const float*)d_in[6];
    const float* W_thL = (const float*)d_in[7];
    const float* W_shU = (const float*)d_in[8];
    const float* W_shL = (const float*)d_in[9];
    const float* table = (const float*)d_in[10];
    const int*   loc   = (const int*)d_in[11];

    float* sp  = (float*)d_ws;                 // NGB * 4 * HDIM partials
    float* t   = sp + NGB * 4 * HDIM;          // 2 * HDIM
    float* out = (float*)d_out;

    void* args[] = { &td_u, &td_l, &ld_u, &ld_l, &hx, &W_ih, &W_thU, &W_thL,
                     &W_shU, &W_shL, &table, &loc, &sp, &t, &out };
    hipLaunchCooperativeKernel((const void*)strnn_fused, dim3(128), dim3(256),
                               args, 0, stream);
}

// Round 3
// 19.112 us; speedup vs baseline: 2.6001x; 2.6001x over previous
//
#include <hip/hip_runtime.h>
#include <math.h>

#define HDIM 512
#define LDIM 256

// Stage 1: 128 blocks x 256 threads.
// Each block redundantly computes the full 4-way weighted row-sum s (in LDS)
// from the gathered table rows (512 KB/block, L2-resident after first touch),
// then computes its 4 rows of t_up / t_lo. No atomics, no memset, no grid sync.
__global__ void __launch_bounds__(256)
k_stage1(const float* __restrict__ td_u, const float* __restrict__ td_l,
         const float* __restrict__ ld_u, const float* __restrict__ ld_l,
         const float* __restrict__ table, const int* __restrict__ loc,
         const float* __restrict__ W_thU, const float* __restrict__ W_thL,
         float* __restrict__ t /* 2*HDIM */) {
    __shared__ float4 w_s[LDIM];     // per-l blend weights (broadcast reads)
    __shared__ int    loc_s[LDIM];
    __shared__ float  s_sm[4 * HDIM];
    const int tid  = threadIdx.x;
    const int wave = tid >> 6;
    const int lane = tid & 63;

    // per-l weights + indices (256 threads == LDIM)
    {
        const int l = tid;
        const float a1 = td_u[l], b1 = td_l[l];
        const float beta = a1 / (a1 + b1);
        const float a2 = ld_u[l], b2 = ld_l[l];
        const float alpha = a2 / (a2 + b2);
        w_s[l] = make_float4(alpha * beta, alpha * (1.f - beta),
                             (1.f - alpha) * beta, (1.f - alpha) * (1.f - beta));
        loc_s[l] = loc[l];
    }
    __syncthreads();

    // each thread owns 2 consecutive h-columns; loop all 256 gathered rows
    const int h2 = tid * 2;
    float a0x = 0, a0y = 0, a1x = 0, a1y = 0, a2x = 0, a2y = 0, a3x = 0, a3y = 0;
#pragma unroll 16
    for (int l = 0; l < LDIM; ++l) {
        const float2 e = *(const float2*)(table + (size_t)loc_s[l] * HDIM + h2);
        const float4 w = w_s[l];
        a0x += w.x * e.x; a0y += w.x * e.y;
        a1x += w.y * e.x; a1y += w.y * e.y;
        a2x += w.z * e.x; a2y += w.z * e.y;
        a3x += w.w * e.x; a3y += w.w * e.y;
    }
    s_sm[0 * HDIM + h2] = a0x; s_sm[0 * HDIM + h2 + 1] = a0y;
    s_sm[1 * HDIM + h2] = a1x; s_sm[1 * HDIM + h2 + 1] = a1y;
    s_sm[2 * HDIM + h2] = a2x; s_sm[2 * HDIM + h2 + 1] = a2y;
    s_sm[3 * HDIM + h2] = a3x; s_sm[3 * HDIM + h2 + 1] = a3y;
    __syncthreads();

    // t rows: one wave per output row
    const int i = blockIdx.x * 4 + wave;
    const float* wu = W_thU + (size_t)i * HDIM;
    const float* wl = W_thL + (size_t)i * HDIM;
    float pu = 0.f, pl = 0.f;
#pragma unroll
    for (int it = 0; it < 2; ++it) {
        const int j = it * 256 + lane * 4;
        const float4 u  = *(const float4*)(wu + j);
        const float4 l4 = *(const float4*)(wl + j);
        const float4 s1 = *(const float4*)(s_sm + 0 * HDIM + j);
        const float4 s2 = *(const float4*)(s_sm + 1 * HDIM + j);
        const float4 s3 = *(const float4*)(s_sm + 2 * HDIM + j);
        const float4 s4 = *(const float4*)(s_sm + 3 * HDIM + j);
        pu += u.x * s1.x + u.y * s1.y + u.z * s1.z + u.w * s1.w
            + l4.x * s2.x + l4.y * s2.y + l4.z * s2.z + l4.w * s2.w;
        pl += u.x * s3.x + u.y * s3.y + u.z * s3.z + u.w * s3.w
            + l4.x * s4.x + l4.y * s4.y + l4.z * s4.z + l4.w * s4.w;
    }
#pragma unroll
    for (int off = 32; off; off >>= 1) {
        pu += __shfl_down(pu, off);
        pl += __shfl_down(pl, off);
    }
    if (lane == 0) { t[i] = pu; t[HDIM + i] = pl; }
}

// Stage 2: out[i] = sigmoid( W_shU[i,:]·t_up + W_shL[i,:]·t_lo + W_ih[i,:]·hx )
__global__ void __launch_bounds__(256)
k_out(const float* __restrict__ WshU, const float* __restrict__ WshL,
      const float* __restrict__ Wih, const float* __restrict__ t,
      const float* __restrict__ hx, float* __restrict__ out) {
    const int wave = threadIdx.x >> 6;
    const int lane = threadIdx.x & 63;
    const int i = blockIdx.x * 4 + wave;
    const float* wu = WshU + (size_t)i * HDIM;
    const float* wl = WshL + (size_t)i * HDIM;
    const float* wi = Wih + (size_t)i * HDIM;
    float p = 0.f;
#pragma unroll
    for (int it = 0; it < 2; ++it) {
        const int j = it * 256 + lane * 4;
        const float4 u   = *(const float4*)(wu + j);
        const float4 l4  = *(const float4*)(wl + j);
        const float4 wi4 = *(const float4*)(wi + j);
        const float4 tu  = *(const float4*)(t + j);
        const float4 tl  = *(const float4*)(t + HDIM + j);
        const float4 hv  = *(const float4*)(hx + j);
        p += u.x * tu.x + u.y * tu.y + u.z * tu.z + u.w * tu.w
           + l4.x * tl.x + l4.y * tl.y + l4.z * tl.z + l4.w * tl.w
           + wi4.x * hv.x + wi4.y * hv.y + wi4.z * hv.z + wi4.w * hv.w;
    }
#pragma unroll
    for (int off = 32; off; off >>= 1) p += __shfl_down(p, off);
    if (lane == 0) out[i] = 1.0f / (1.0f + expf(-p));
}

extern "C" void kernel_launch(void* const* d_in, const int* in_sizes, int n_in,
                              void* d_out, int out_size, void* d_ws, size_t ws_size,
                              hipStream_t stream) {
    const float* td_u  = (const float*)d_in[0];
    const float* td_l  = (const float*)d_in[1];
    const float* ld_u  = (const float*)d_in[2];
    const float* ld_l  = (const float*)d_in[3];
    const float* hx    = (const float*)d_in[4];
    const float* W_ih  = (const float*)d_in[5];
    const float* W_thU = (const float*)d_in[6];
    const float* W_thL = (const float*)d_in[7];
    const float* W_shU = (const float*)d_in[8];
    const float* W_shL = (const float*)d_in[9];
    const float* table = (const float*)d_in[10];
    const int*   loc   = (const int*)d_in[11];

    float* t   = (float*)d_ws;   // 2*HDIM intermediate
    float* out = (float*)d_out;

    k_stage1<<<HDIM / 4, 256, 0, stream>>>(td_u, td_l, ld_u, ld_l, table, loc,
                                           W_thU, W_thL, t);
    k_out<<<HDIM / 4, 256, 0, stream>>>(W_shU, W_shL, W_ih, t, hx, out);
}

// Round 4
// 14.016 us; speedup vs baseline: 3.5453x; 1.3636x over previous
//
#include <hip/hip_runtime.h>
#include <math.h>

#define HDIM 512
#define LDIM 256

__device__ __forceinline__ void fma4(float4& a, float w, const float4& e) {
    a.x += w * e.x; a.y += w * e.y; a.z += w * e.z; a.w += w * e.w;
}

// Node 1: 64 blocks x 512 threads (8 waves).
// Each block redundantly computes s = 4 weighted row-sums of the gathered
// table rows, split across 4 row-groups of 128 threads (64 rows each,
// float4 loads, 16 in flight), reduced via LDS; then 8 t-rows (1 per wave).
__global__ void __launch_bounds__(512)
k_stage1(const float* __restrict__ td_u, const float* __restrict__ td_l,
         const float* __restrict__ ld_u, const float* __restrict__ ld_l,
         const float* __restrict__ table, const int* __restrict__ loc,
         const float* __restrict__ W_thU, const float* __restrict__ W_thL,
         float* __restrict__ t /* 2*HDIM */) {
    __shared__ float4 w_s[LDIM];          // 4 KB
    __shared__ int    loc_s[LDIM];        // 1 KB
    __shared__ float  part[4][4 * HDIM];  // 32 KB per-group partial s
    __shared__ float  s_sm[4 * HDIM];     // 8 KB
    const int tid  = threadIdx.x;
    const int wave = tid >> 6;
    const int lane = tid & 63;

    if (tid < LDIM) {
        const int l = tid;
        const float a1 = td_u[l], b1 = td_l[l];
        const float beta = a1 / (a1 + b1);
        const float a2 = ld_u[l], b2 = ld_l[l];
        const float alpha = a2 / (a2 + b2);
        w_s[l] = make_float4(alpha * beta, alpha * (1.0f - beta),
                             (1.0f - alpha) * beta, (1.0f - alpha) * (1.0f - beta));
        loc_s[l] = loc[l];
    }
    __syncthreads();

    // ---- gather: group g sums rows [g*64, g*64+64), thread owns 4 h-cols ----
    const int g  = tid >> 7;      // 0..3
    const int c  = tid & 127;     // col-owner within group
    const int h4 = c * 4;
    float4 a0 = {0,0,0,0}, a1v = {0,0,0,0}, a2v = {0,0,0,0}, a3v = {0,0,0,0};
    const int lbase = g * 64;
    for (int base = 0; base < 64; base += 16) {
        float4 e[16];
#pragma unroll
        for (int k = 0; k < 16; ++k)
            e[k] = *(const float4*)(table + (size_t)loc_s[lbase + base + k] * HDIM + h4);
#pragma unroll
        for (int k = 0; k < 16; ++k) {
            const float4 w = w_s[lbase + base + k];
            fma4(a0,  w.x, e[k]);
            fma4(a1v, w.y, e[k]);
            fma4(a2v, w.z, e[k]);
            fma4(a3v, w.w, e[k]);
        }
    }
    *(float4*)(&part[g][0 * HDIM + h4]) = a0;
    *(float4*)(&part[g][1 * HDIM + h4]) = a1v;
    *(float4*)(&part[g][2 * HDIM + h4]) = a2v;
    *(float4*)(&part[g][3 * HDIM + h4]) = a3v;
    __syncthreads();

    // ---- reduce 4 group-partials: thread owns float4 slot tid*4 of 2048 ----
    {
        const int s0 = tid * 4;
        float4 r = {0,0,0,0};
#pragma unroll
        for (int p = 0; p < 4; ++p) {
            const float4 v = *(const float4*)(&part[p][s0]);
            r.x += v.x; r.y += v.y; r.z += v.z; r.w += v.w;
        }
        *(float4*)(&s_sm[s0]) = r;
    }
    __syncthreads();

    // ---- t rows: one per wave ----
    const int i = blockIdx.x * 8 + wave;
    const float* wu = W_thU + (size_t)i * HDIM;
    const float* wl = W_thL + (size_t)i * HDIM;
    float pu = 0.f, pl = 0.f;
#pragma unroll
    for (int it = 0; it < 2; ++it) {
        const int j = it * 256 + lane * 4;
        const float4 u  = *(const float4*)(wu + j);
        const float4 l4 = *(const float4*)(wl + j);
        const float4 s1 = *(const float4*)(s_sm + 0 * HDIM + j);
        const float4 s2 = *(const float4*)(s_sm + 1 * HDIM + j);
        const float4 s3 = *(const float4*)(s_sm + 2 * HDIM + j);
        const float4 s4 = *(const float4*)(s_sm + 3 * HDIM + j);
        pu += u.x * s1.x + u.y * s1.y + u.z * s1.z + u.w * s1.w
            + l4.x * s2.x + l4.y * s2.y + l4.z * s2.z + l4.w * s2.w;
        pl += u.x * s3.x + u.y * s3.y + u.z * s3.z + u.w * s3.w
            + l4.x * s4.x + l4.y * s4.y + l4.z * s4.z + l4.w * s4.w;
    }
#pragma unroll
    for (int off = 32; off; off >>= 1) {
        pu += __shfl_down(pu, off);
        pl += __shfl_down(pl, off);
    }
    if (lane == 0) { t[i] = pu; t[HDIM + i] = pl; }
}

// Node 2: out[i] = sigmoid( W_shU[i,:]·t_up + W_shL[i,:]·t_lo + W_ih[i,:]·hx )
__global__ void __launch_bounds__(256)
k_out(const float* __restrict__ WshU, const float* __restrict__ WshL,
      const float* __restrict__ Wih, const float* __restrict__ t,
      const float* __restrict__ hx, float* __restrict__ out) {
    const int wave = threadIdx.x >> 6;
    const int lane = threadIdx.x & 63;
    const int i = blockIdx.x * 4 + wave;
    const float* wu = WshU + (size_t)i * HDIM;
    const float* wl = WshL + (size_t)i * HDIM;
    const float* wi = Wih + (size_t)i * HDIM;
    float p = 0.f;
#pragma unroll
    for (int it = 0; it < 2; ++it) {
        const int j = it * 256 + lane * 4;
        const float4 u   = *(const float4*)(wu + j);
        const float4 l4  = *(const float4*)(wl + j);
        const float4 wi4 = *(const float4*)(wi + j);
        const float4 tu  = *(const float4*)(t + j);
        const float4 tl  = *(const float4*)(t + HDIM + j);
        const float4 hv  = *(const float4*)(hx + j);
        p += u.x * tu.x + u.y * tu.y + u.z * tu.z + u.w * tu.w
           + l4.x * tl.x + l4.y * tl.y + l4.z * tl.z + l4.w * tl.w
           + wi4.x * hv.x + wi4.y * hv.y + wi4.z * hv.z + wi4.w * hv.w;
    }
#pragma unroll
    for (int off = 32; off; off >>= 1) p += __shfl_down(p, off);
    if (lane == 0) out[i] = 1.0f / (1.0f + expf(-p));
}

extern "C" void kernel_launch(void* const* d_in, const int* in_sizes, int n_in,
                              void* d_out, int out_size, void* d_ws, size_t ws_size,
                              hipStream_t stream) {
    const float* td_u  = (const float*)d_in[0];
    const float* td_l  = (const float*)d_in[1];
    const float* ld_u  = (const float*)d_in[2];
    const float* ld_l  = (const float*)d_in[3];
    const float* hx    = (const float*)d_in[4];
    const float* W_ih  = (const float*)d_in[5];
    const float* W_thU = (const float*)d_in[6];
    const float* W_thL = (const float*)d_in[7];
    const float* W_shU = (const float*)d_in[8];
    const float* W_shL = (const float*)d_in[9];
    const float* table = (const float*)d_in[10];
    const int*   loc   = (const int*)d_in[11];

    float* t   = (float*)d_ws;   // 2*HDIM intermediate
    float* out = (float*)d_out;

    k_stage1<<<64, 512, 0, stream>>>(td_u, td_l, ld_u, ld_l, table, loc,
                                     W_thU, W_thL, t);
    k_out<<<HDIM / 4, 256, 0, stream>>>(W_shU, W_shL, W_ih, t, hx, out);
}